// Round 20
// baseline (84.929 us; speedup 1.0000x reference)
//
#include <hip/hip_runtime.h>
#include <hip/hip_bf16.h>

#define NB 1024
#define NH 256
#define EMB 128
#define TWOD 256
#define HID 256
#define ROWS 128            // history rows per block
#define BPB 2               // blocks per batch element
#define NBLK (NB * BPB)

typedef __attribute__((ext_vector_type(4))) float f32x4;
typedef __attribute__((ext_vector_type(8))) short bf16x8;

__device__ __forceinline__ unsigned short f2bf(float f) {
  union { float f; unsigned u; } v; v.f = f;
  unsigned u = v.u;
  unsigned r = (u + 0x7fffu + ((u >> 16) & 1u)) >> 16;
  return (unsigned short)r;
}

// W1 [d=256][n=256] fp32 -> W1T [n][d] bf16, coalesced both sides via LDS
// tile transpose (16 blocks of 64x64 tiles).
__global__ __launch_bounds__(256) void prep_w1t(const float* __restrict__ W1,
                                                unsigned short* __restrict__ W1T) {
  const int bx = blockIdx.x & 3;        // d-tile
  const int by = blockIdx.x >> 2;       // n-tile
  __shared__ float tile[64][65];        // +1 pad: conflict-free transpose read
  const int tr = threadIdx.x >> 6;      // 0..3
  const int tc = threadIdx.x & 63;      // 0..63
  #pragma unroll
  for (int i = 0; i < 16; ++i) {
    const int d = bx * 64 + i * 4 + tr;
    tile[i * 4 + tr][tc] = W1[(size_t)d * HID + by * 64 + tc];
  }
  __syncthreads();
  #pragma unroll
  for (int i = 0; i < 16; ++i) {
    const int n = by * 64 + i * 4 + tr;
    W1T[(size_t)n * TWOD + bx * 64 + tc] = f2bf(tile[tc][i * 4 + tr]);
  }
}

// 2048 blocks (2 per batch element), 512 threads = 8 waves, 128 rows per block.
// R19 structure (scalar-pipe keys + DMA hist gather + parallel reg gather +
// in-place fold) with two serialization trims:
//  - split vmcnt: issue order pinned {t-loads, 8 DMA} | {8 vb}; hist fold
//    waits vmcnt(8) (DMAs+t only), reg fold waits vmcnt(0) -> vb latency
//    overlaps the ~100-op hist fold.
//  - keys stashed to items_lds from SGPRs during the DMA loop -> P3's mask
//    read comes from LDS, not a tail-latency global re-read.
__global__ __launch_bounds__(512, 4) void nais_main(
    const int* __restrict__ history, const int* __restrict__ target,
    const int* __restrict__ hregion, const int* __restrict__ tregion,
    const float* __restrict__ E_hist, const float* __restrict__ E_targ,
    const float* __restrict__ E_reg,
    const unsigned short* __restrict__ W1T, const float* __restrict__ b1,
    const float* __restrict__ w2,
    float* __restrict__ part_se, float* __restrict__ part_sd)
{
  const int blk = blockIdx.x;
  const int b = blk >> 1;
  const int r0 = (blk & 1) * ROWS;      // row offset within the 256-history
  const int tid = threadIdx.x;
  const int lane = tid & 63;
  const int wave = tid >> 6;            // 0..7
  const int wave_s = __builtin_amdgcn_readfirstlane(wave);  // provably scalar
  const int l15 = lane & 15;
  const int lhi = lane >> 4;
  const int l31 = lane & 31;

  __shared__ __align__(16) unsigned short inp_lds[ROWS * 256];  // 64 KiB
  __shared__ float dot_lds[ROWS];
  __shared__ int items_lds[ROWS];
  __shared__ float score_parts[8][ROWS];

  const int tgt_item = target[b];

  // ---- P1 (per-wave, no coupling): DMA hist fp32 + reg gather + fold ----
  {
    const int rsel = lane >> 5;         // which row of each 2-row pair

    // (0) target slices FIRST (oldest in vmcnt retirement order)
    const f32x4 t4r = *(const f32x4*)(E_reg + (size_t)tregion[b] * EMB + l31 * 4);
    const float2 t2h = *(const float2*)(E_targ + (size_t)tgt_item * EMB + lane * 2);
    __builtin_amdgcn_sched_barrier(0);

    // (1) DMA: 8 instrs x 2 rows; scalar keys (s_load); keys stashed to LDS
    #pragma unroll
    for (int i = 0; i < 8; ++i) {
      const int wr0 = wave_s * 16 + i * 2;
      const int kh0 = history[b * NH + r0 + wr0];       // s_load_dword
      const int kh1 = history[b * NH + r0 + wr0 + 1];   // s_load_dword
      if (lane == 0) { items_lds[wr0] = kh0; items_lds[wr0 + 1] = kh1; }
      const int kh = rsel ? kh1 : kh0;
      const float* src = E_hist + (size_t)kh * EMB + (lane & 31) * 4;
      __builtin_amdgcn_global_load_lds(
          (const __attribute__((address_space(1))) void*)src,
          (__attribute__((address_space(3))) void*)&inp_lds[wr0 * 256],
          16, 0, 0);
    }
    __builtin_amdgcn_sched_barrier(0);

    // (2) E_reg gather (L2-hot): scalar keys, f32x4 per lane — may stay
    //     outstanding through the hist fold below
    f32x4 vb[8];
    #pragma unroll
    for (int i = 0; i < 8; ++i) {
      const int wr0 = wave_s * 16 + i * 2;
      const int kr0 = hregion[b * NH + r0 + wr0];       // s_load_dword
      const int kr1 = hregion[b * NH + r0 + wr0 + 1];   // s_load_dword
      const int kr = rsel ? kr1 : kr0;
      vb[i] = *(const f32x4*)(E_reg + (size_t)kr * EMB + l31 * 4);
    }
    __builtin_amdgcn_sched_barrier(0);

    // (3) wait t-loads + DMAs only: 8 vb loads may remain in flight
    asm volatile("s_waitcnt vmcnt(8)" ::: "memory");
    __builtin_amdgcn_sched_barrier(0);

    // (4) hist fold in place: lane reads fp32 pair (bytes 8L..8L+8 of row),
    //     writes bf16 pair to swizzled granule in bytes 0..255
    #pragma unroll
    for (int s = 0; s < 16; ++s) {
      const int row = wave_s * 16 + s;
      const char* rbase = (const char*)&inp_lds[row * 256];
      float2 f = *(const float2*)(rbase + lane * 8);
      float2 v; v.x = f.x * t2h.x; v.y = f.y * t2h.y;
      union { __hip_bfloat162 h; unsigned u; } c;
      c.h = __float22bfloat162_rn(v);
      const int g = lane >> 2;                          // granule 0..15
      const int gs = g ^ (row & 7) ^ ((g >> 3) & 3);    // swizzle (bijective/row)
      *(unsigned*)((char*)&inp_lds[row * 256] + gs * 16 + (lane & 3) * 4) = c.u;
    }

    // (5) wait vb, then reg fold into bytes 256..511 (consumed above as fp32)
    asm volatile("s_waitcnt vmcnt(0)" ::: "memory");
    __builtin_amdgcn_sched_barrier(0);
    #pragma unroll
    for (int i = 0; i < 8; ++i) {
      const int row = wave_s * 16 + i * 2 + rsel;
      f32x4 v = vb[i] * t4r;
      float2 f01; f01.x = v[0]; f01.y = v[1];
      float2 f23; f23.x = v[2]; f23.y = v[3];
      union { __hip_bfloat162 h; unsigned u; } c0, c1;
      c0.h = __float22bfloat162_rn(f01);
      c1.h = __float22bfloat162_rn(f23);
      const int g = 16 + (l31 >> 1);                    // granule 16..31
      const int gs = g ^ (row & 7) ^ ((g >> 3) & 3);
      unsigned* dst = (unsigned*)((char*)&inp_lds[row * 256] + gs * 16 + (l31 & 1) * 8);
      dst[0] = c0.u; dst[1] = c1.u;
    }
  }
  __syncthreads();

  // ---- P2: GEMM. wave owns cols [wave*32, wave*32+32); kk outer,
  //      both 64-row chunks inner -> each bfr load feeds 16 MFMAs ----
  {
    const int col0 = wave * 32;
    float b1v[2], w2v[2];
    #pragma unroll
    for (int n = 0; n < 2; ++n) {
      const int colh = col0 + n * 16 + l15;
      b1v[n] = b1[colh];
      w2v[n] = w2[colh];
    }

    f32x4 acc[2][4][2];
    #pragma unroll
    for (int c = 0; c < 2; ++c)
      #pragma unroll
      for (int m = 0; m < 4; ++m)
        #pragma unroll
        for (int n = 0; n < 2; ++n)
          acc[c][m][n] = (f32x4){0.f, 0.f, 0.f, 0.f};

    #pragma unroll
    for (int kk = 0; kk < 8; ++kk) {
      bf16x8 bfr[2];
      #pragma unroll
      for (int n = 0; n < 2; ++n) {
        const int colh = col0 + n * 16 + l15;
        bfr[n] = *(const bf16x8*)(W1T + (size_t)colh * TWOD + kk * 32 + lhi * 8);
      }
      bf16x8 af[2][4];
      #pragma unroll
      for (int c = 0; c < 2; ++c)
        #pragma unroll
        for (int m = 0; m < 4; ++m) {
          const int row = c * 64 + m * 16 + l15;
          const int gk = kk * 4 + lhi;
          const int gs = gk ^ (row & 7) ^ ((gk >> 3) & 3);
          af[c][m] = *(const bf16x8*)(&inp_lds[row * 256 + gs * 8]);
        }
      __builtin_amdgcn_s_setprio(1);
      #pragma unroll
      for (int c = 0; c < 2; ++c)
        #pragma unroll
        for (int m = 0; m < 4; ++m)
          #pragma unroll
          for (int n = 0; n < 2; ++n)
            acc[c][m][n] = __builtin_amdgcn_mfma_f32_16x16x32_bf16(af[c][m], bfr[n], acc[c][m][n], 0, 0, 0);
      __builtin_amdgcn_s_setprio(0);
    }

    // ---- dot_ht from the LDS tile: wave's own 16 rows, 4 lanes/row ----
    {
      const int drow = wave * 16 + (lane >> 2);
      const int seg = lane & 3;
      float dsum = 0.f;
      #pragma unroll
      for (int j = 0; j < 8; ++j) {
        const int gidx = seg * 8 + ((j + drow) & 7);          // rotated
        const int gs = gidx ^ (drow & 7) ^ (seg & 3);         // same swizzle
        union { bf16x8 w; unsigned u[4]; } a;
        a.w = *(const bf16x8*)(&inp_lds[drow * 256 + gs * 8]);
        #pragma unroll
        for (int q = 0; q < 4; ++q) {
          union { unsigned u; float f; } lo, hi;
          lo.u = a.u[q] << 16;
          hi.u = a.u[q] & 0xFFFF0000u;
          dsum += lo.f + hi.f;
        }
      }
      dsum += __shfl_xor(dsum, 1);
      dsum += __shfl_xor(dsum, 2);
      if (seg == 0) dot_lds[drow] = dsum;
    }

    // epilogue: relu + b1, dot with w2, 16-lane reduce -> score_parts[wave][row]
    #pragma unroll
    for (int c = 0; c < 2; ++c) {
      #pragma unroll
      for (int m = 0; m < 4; ++m) {
        #pragma unroll
        for (int r = 0; r < 4; ++r) {
          float p = 0.f;
          #pragma unroll
          for (int n = 0; n < 2; ++n) {
            float hv = acc[c][m][n][r] + b1v[n];  // C/D: col=lane&15, row=(lane>>4)*4+r
            hv = hv > 0.f ? hv : 0.f;
            p += hv * w2v[n];
          }
          p += __shfl_xor(p, 1);
          p += __shfl_xor(p, 2);
          p += __shfl_xor(p, 4);
          p += __shfl_xor(p, 8);
          if (l15 == 0) score_parts[wave][c * 64 + m * 16 + lhi * 4 + r] = p;
        }
      }
    }
  }
  __syncthreads();

  // ---- P3: masked exp + partial sums -> per-(block,wave) ws slots ----
  if (wave < 2) {
    const int lrow = wave * 64 + lane;
    float sc = 0.f;
    #pragma unroll
    for (int w = 0; w < 8; ++w) sc += score_parts[w][lrow];
    float e = (items_lds[lrow] != tgt_item) ? expf(sc) : 0.f;
    float ed = e * dot_lds[lrow];
    #pragma unroll
    for (int off = 32; off >= 1; off >>= 1) {
      e += __shfl_xor(e, off);
      ed += __shfl_xor(ed, off);
    }
    if (lane == 0) {
      part_se[blk * 2 + wave] = e;
      part_sd[blk * 2 + wave] = ed;
    }
  }
}

__global__ __launch_bounds__(256) void finalize(const float* __restrict__ part_se,
                                                const float* __restrict__ part_sd,
                                                float* __restrict__ out) {
  const int b = blockIdx.x * 256 + threadIdx.x;
  if (b < NB) {
    float se = 0.f, sd = 0.f;
    #pragma unroll
    for (int i = 0; i < BPB * 2; ++i) {
      se += part_se[b * BPB * 2 + i];
      sd += part_sd[b * BPB * 2 + i];
    }
    const float pred = (se > 0.f) ? (sd / sqrtf(se)) : 0.f;  // denom = sum^0.5
    out[b] = 1.f / (1.f + expf(-pred));
  }
}

extern "C" void kernel_launch(void* const* d_in, const int* in_sizes, int n_in,
                              void* d_out, int out_size, void* d_ws, size_t ws_size,
                              hipStream_t stream) {
  const int* history = (const int*)d_in[0];
  const int* target  = (const int*)d_in[1];
  const int* hregion = (const int*)d_in[2];
  const int* tregion = (const int*)d_in[3];
  const float* E_hist = (const float*)d_in[4];
  const float* E_targ = (const float*)d_in[5];
  const float* E_reg  = (const float*)d_in[6];
  const float* W1 = (const float*)d_in[7];
  const float* b1 = (const float*)d_in[8];
  const float* w2 = (const float*)d_in[9];
  float* out = (float*)d_out;

  char* p = (char*)d_ws;
  unsigned short* W1T = (unsigned short*)p;  p += (size_t)TWOD * HID * 2;   // 128 KB
  float* part_se = (float*)p;                p += (size_t)NBLK * 2 * 4;     // 16 KB
  float* part_sd = (float*)p;

  prep_w1t<<<16, 256, 0, stream>>>(W1, W1T);
  nais_main<<<NBLK, 512, 0, stream>>>(history, target, hregion, tregion,
                                      E_hist, E_targ, E_reg, W1T, b1, w2,
                                      part_se, part_sd);
  finalize<<<(NB + 255) / 256, 256, 0, stream>>>(part_se, part_sd, out);
}